// Round 1
// baseline (1519.464 us; speedup 1.0000x reference)
//
#include <hip/hip_runtime.h>
#include <math.h>

#define TILE 64
#define KT   16
#define PAD  68   // KT-row leading dim: +4 pad keeps float4 alignment, breaks pow2 bank stride

// ---------------- mean over M per (b,c) row ----------------
__global__ __launch_bounds__(256) void mean_kernel(const float* __restrict__ x,
                                                   float* __restrict__ mu, int M) {
    int row = blockIdx.x;                       // b*C + c
    const float* xr = x + (size_t)row * M;
    float s = 0.f;
    for (int m = threadIdx.x; m < M; m += 256) s += xr[m];
    #pragma unroll
    for (int off = 32; off > 0; off >>= 1) s += __shfl_down(s, off, 64);
    __shared__ float red[4];
    int lane = threadIdx.x & 63, wv = threadIdx.x >> 6;
    if (lane == 0) red[wv] = s;
    __syncthreads();
    if (threadIdx.x == 0) mu[row] = (red[0] + red[1] + red[2] + red[3]) / (float)M;
}

// ---------------- cov = X@X^T / M - mu mu^T  (per batch, 512x512 from 512x784) ----------------
__global__ __launch_bounds__(256) void gram_kernel(const float* __restrict__ x,
                                                   const float* __restrict__ mu,
                                                   float* __restrict__ cov) {
    const int C = 512, M = 784;
    int b = blockIdx.z;
    const float* X = x + (size_t)b * C * M;
    __shared__ float As[KT][PAD];
    __shared__ float Bs[KT][PAD];
    int tid = threadIdx.x;
    int tx = tid & 15, ty = tid >> 4;
    int row0 = blockIdx.y * TILE, col0 = blockIdx.x * TILE;
    int lr = tid >> 2, lk = (tid & 3) << 2;     // each thread: one float4 along k
    float acc[4][4] = {};
    for (int k0 = 0; k0 < M; k0 += KT) {
        float4 a4 = *(const float4*)(X + (size_t)(row0 + lr) * M + (k0 + lk));
        float4 b4 = *(const float4*)(X + (size_t)(col0 + lr) * M + (k0 + lk));
        __syncthreads();
        As[lk+0][lr] = a4.x; As[lk+1][lr] = a4.y; As[lk+2][lr] = a4.z; As[lk+3][lr] = a4.w;
        Bs[lk+0][lr] = b4.x; Bs[lk+1][lr] = b4.y; Bs[lk+2][lr] = b4.z; Bs[lk+3][lr] = b4.w;
        __syncthreads();
        #pragma unroll
        for (int k = 0; k < KT; ++k) {
            float4 av = *(const float4*)&As[k][ty << 2];
            float4 bv = *(const float4*)&Bs[k][tx << 2];
            float a[4] = {av.x, av.y, av.z, av.w};
            float bb[4] = {bv.x, bv.y, bv.z, bv.w};
            #pragma unroll
            for (int i = 0; i < 4; ++i)
                #pragma unroll
                for (int j = 0; j < 4; ++j) acc[i][j] += a[i] * bb[j];
        }
    }
    const float invM = 1.0f / 784.0f;
    float* Cb = cov + (size_t)b * C * C;
    const float* mub = mu + b * C;
    #pragma unroll
    for (int i = 0; i < 4; ++i) {
        int r = row0 + (ty << 2) + i;
        float mr = mub[r];
        #pragma unroll
        for (int j = 0; j < 4; ++j) {
            int c = col0 + (tx << 2) + j;
            Cb[(size_t)r * C + c] = acc[i][j] * invM - mr * mub[c];
        }
    }
}

// ---------------- trace per batch ----------------
__global__ __launch_bounds__(512) void trace_kernel(const float* __restrict__ cov,
                                                    float* __restrict__ tr) {
    const int C = 512;
    int b = blockIdx.x;
    float s = cov[(size_t)b * C * C + (size_t)threadIdx.x * C + threadIdx.x];
    #pragma unroll
    for (int off = 32; off > 0; off >>= 1) s += __shfl_down(s, off, 64);
    __shared__ float red[8];
    int lane = threadIdx.x & 63, wv = threadIdx.x >> 6;
    if (lane == 0) red[wv] = s;
    __syncthreads();
    if (threadIdx.x == 0) {
        float t = 0.f;
        #pragma unroll
        for (int i = 0; i < 8; ++i) t += red[i];
        tr[b] = t;
    }
}

// ---------------- Y0 = cov/tr ; Z1 = 0.5*(3I - Y0)   (iter-1 ZY is elementwise since Z0=I) ----------------
__global__ __launch_bounds__(256) void prep_kernel(float* __restrict__ Y,
                                                   float* __restrict__ Z,
                                                   const float* __restrict__ tr) {
    const int C = 512;
    size_t i = (size_t)blockIdx.x * 256 + threadIdx.x;   // one float4 per thread, exact grid
    int perb = (C * C) >> 2;                              // 65536
    int b = (int)(i / perb);
    int rem = (int)(i % perb);
    int r = rem >> 7;                // rem / (C/4)
    int c4 = (rem & 127) << 2;
    float invt = 1.0f / tr[b];
    float4 v = ((const float4*)Y)[i];
    float4 y;
    y.x = v.x * invt; y.y = v.y * invt; y.z = v.z * invt; y.w = v.w * invt;
    ((float4*)Y)[i] = y;
    float4 z;
    z.x = 0.5f * (((c4 + 0) == r ? 3.0f : 0.0f) - y.x);
    z.y = 0.5f * (((c4 + 1) == r ? 3.0f : 0.0f) - y.y);
    z.z = 0.5f * (((c4 + 2) == r ? 3.0f : 0.0f) - y.z);
    z.w = 0.5f * (((c4 + 3) == r ? 3.0f : 0.0f) - y.w);
    ((float4*)Z)[i] = z;
}

// ---------------- batched 512x512x512 GEMM, MODE 0: C=A@B ; MODE 1: C=0.5*(3I - A@B) ----------------
template <int MODE>
__global__ __launch_bounds__(256) void gemm512(const float* __restrict__ A,
                                               const float* __restrict__ B,
                                               float* __restrict__ C) {
    const int N = 512;
    int b = blockIdx.z;
    A += (size_t)b * N * N;
    B += (size_t)b * N * N;
    C += (size_t)b * N * N;
    __shared__ float As[KT][PAD];
    __shared__ float Bs[KT][PAD];
    int tid = threadIdx.x;
    int tx = tid & 15, ty = tid >> 4;
    int row0 = blockIdx.y * TILE, col0 = blockIdx.x * TILE;
    int alr = tid >> 2, alk = (tid & 3) << 2;   // A: row alr, k-float4 at alk
    int bk = tid >> 4, bd = (tid & 15) << 2;    // B: k-row bk, col-float4 at bd
    float acc[4][4] = {};
    for (int k0 = 0; k0 < N; k0 += KT) {
        float4 a4 = *(const float4*)(A + (size_t)(row0 + alr) * N + (k0 + alk));
        float4 b4 = *(const float4*)(B + (size_t)(k0 + bk) * N + (col0 + bd));
        __syncthreads();
        As[alk+0][alr] = a4.x; As[alk+1][alr] = a4.y; As[alk+2][alr] = a4.z; As[alk+3][alr] = a4.w;
        *(float4*)&Bs[bk][bd] = b4;
        __syncthreads();
        #pragma unroll
        for (int k = 0; k < KT; ++k) {
            float4 av = *(const float4*)&As[k][ty << 2];
            float4 bv = *(const float4*)&Bs[k][tx << 2];
            float a[4] = {av.x, av.y, av.z, av.w};
            float bb[4] = {bv.x, bv.y, bv.z, bv.w};
            #pragma unroll
            for (int i = 0; i < 4; ++i)
                #pragma unroll
                for (int j = 0; j < 4; ++j) acc[i][j] += a[i] * bb[j];
        }
    }
    #pragma unroll
    for (int i = 0; i < 4; ++i) {
        int r = row0 + (ty << 2) + i;
        #pragma unroll
        for (int j = 0; j < 4; ++j) {
            int c = col0 + (tx << 2) + j;
            float v = acc[i][j];
            if (MODE == 1) v = 0.5f * ((r == c ? 3.0f : 0.0f) - v);
            C[(size_t)r * N + c] = v;
        }
    }
}

// ---------------- scale[b,d] = 0.5*(3*r - (r@Z)@Y)[d] * sqrt(tr), r = colmean(Y) ----------------
__global__ __launch_bounds__(512) void colmean_final(const float* __restrict__ Y,
                                                     const float* __restrict__ Z,
                                                     const float* __restrict__ tr,
                                                     float* __restrict__ scale) {
    const int C = 512;
    int b = blockIdx.x;
    const float* Yb = Y + (size_t)b * C * C;
    const float* Zb = Z + (size_t)b * C * C;
    __shared__ float u[512];
    __shared__ float v[512];
    int d = threadIdx.x;
    float s = 0.f;
    for (int c = 0; c < C; ++c) s += Yb[(size_t)c * C + d];
    u[d] = s * (1.0f / 512.0f);
    __syncthreads();
    float s2 = 0.f;
    for (int c = 0; c < C; ++c) s2 += u[c] * Zb[(size_t)c * C + d];
    v[d] = s2;
    __syncthreads();
    float s3 = 0.f;
    for (int c = 0; c < C; ++c) s3 += v[c] * Yb[(size_t)c * C + d];
    scale[b * C + d] = 0.5f * (3.0f * u[d] - s3) * sqrtf(tr[b]);
}

// ---------------- out = scale[b,ch] * x ----------------
__global__ __launch_bounds__(256) void scale_x(const float* __restrict__ x,
                                               const float* __restrict__ scale,
                                               float* __restrict__ out, size_t total4) {
    size_t i = (size_t)blockIdx.x * 256 + threadIdx.x;
    if (i >= total4) return;
    const int HW4 = 784 / 4;                 // 196 float4 per channel
    size_t ch = i / HW4;                     // b*C + c
    float sc = scale[ch];
    float4 v = ((const float4*)x)[i];
    v.x *= sc; v.y *= sc; v.z *= sc; v.w *= sc;
    ((float4*)out)[i] = v;
}

extern "C" void kernel_launch(void* const* d_in, const int* in_sizes, int n_in,
                              void* d_out, int out_size, void* d_ws, size_t ws_size,
                              hipStream_t stream) {
    const int B = 32, C = 512, M = 784;
    const size_t mat = (size_t)C * C;         // 262144 floats per batch matrix
    const float* x = (const float*)d_in[0];
    float* out = (float*)d_out;

    float* ws = (float*)d_ws;
    // small vectors first
    float* mu    = ws;                        // B*C
    float* tr    = mu + (size_t)B * C;        // B
    float* scale = tr + B;                    // B*C
    float* Y     = scale + (size_t)B * C;
    float* Y2    = Y  + (size_t)B * mat;
    float* Z     = Y2 + (size_t)B * mat;
    float* Z2    = Z  + (size_t)B * mat;
    size_t used4 = (size_t)(Z2 + (size_t)B * mat - ws);
    float* T;
    if (ws_size >= (used4 + (size_t)B * mat) * sizeof(float)) {
        T = Z2 + (size_t)B * mat;             // fits in workspace
    } else {
        T = out;                              // d_out as scratch (51.4 MB >= 33.5 MB); final result overwrites later
    }

    dim3 g88(8, 8, B);

    // 1) per-row means
    mean_kernel<<<B * C, 256, 0, stream>>>(x, mu, M);
    // 2) covariance into Y
    gram_kernel<<<g88, 256, 0, stream>>>(x, mu, Y);
    // 3) trace (normA)
    trace_kernel<<<B, 512, 0, stream>>>(Y, tr);
    // 4) Y0 = cov/tr ; Z = ZY0 = 0.5*(3I - Y0)  (== Z1 since Z0 = I)
    prep_kernel<<<(B * (int)mat) / 4 / 256, 256, 0, stream>>>(Y, Z, tr);
    // 5) iter 1: Y1 = Y0 @ ZY0
    gemm512<0><<<g88, 256, 0, stream>>>(Y, Z, Y2);
    { float* t = Y; Y = Y2; Y2 = t; }
    // 6) iters 2..4: T = 0.5(3I - Z@Y); Y <- Y@T; Z <- T@Z
    for (int it = 0; it < 3; ++it) {
        gemm512<1><<<g88, 256, 0, stream>>>(Z, Y, T);
        gemm512<0><<<g88, 256, 0, stream>>>(Y, T, Y2);
        gemm512<0><<<g88, 256, 0, stream>>>(T, Z, Z2);
        { float* t = Y; Y = Y2; Y2 = t; }
        { float* t = Z; Z = Z2; Z2 = t; }
    }
    // 7) channel scales from colmean of final NS step (vector-matrix, no full matmuls)
    colmean_final<<<B, 512, 0, stream>>>(Y, Z, tr, scale);
    // 8) out = scale * x
    size_t total4 = (size_t)B * C * M / 4;    // 3,211,264
    scale_x<<<(int)((total4 + 255) / 256), 256, 0, stream>>>(x, scale, out, total4);
}

// Round 2
// 703.594 us; speedup vs baseline: 2.1596x; 2.1596x over previous
//
#include <hip/hip_runtime.h>
#include <math.h>

typedef short bf8 __attribute__((ext_vector_type(8)));   // 8 bf16 = 4 VGPRs
typedef float f4 __attribute__((ext_vector_type(4)));

__device__ inline unsigned short f2bf(float f) {          // RNE f32 -> bf16
    unsigned int u = __float_as_uint(f);
    u = u + 0x7fffu + ((u >> 16) & 1u);
    return (unsigned short)(u >> 16);
}
__device__ inline float bf2f(unsigned short h) {
    return __uint_as_float(((unsigned int)h) << 16);
}
__device__ inline void split_bf(float v, unsigned short& h, unsigned short& l) {
    h = f2bf(v);
    l = f2bf(v - bf2f(h));
}
__device__ inline void async16(const void* g, void* l) {
    __builtin_amdgcn_global_load_lds(
        (const __attribute__((address_space(1))) unsigned int*)g,
        (__attribute__((address_space(3))) unsigned int*)l, 16, 0, 0);
}

// ---------- fuse row-mean + center + bf16 hi/lo split (K padded 784->800 with zeros) ----------
__global__ __launch_bounds__(256) void center_convert(const float* __restrict__ x,
        unsigned short* __restrict__ Xh, unsigned short* __restrict__ Xl) {
    int row = blockIdx.x;                       // b*512 + c
    const float* xr = x + (size_t)row * 784;
    int t = threadIdx.x;
    float4 vv = {0.f, 0.f, 0.f, 0.f};
    if (t < 196) vv = *(const float4*)(xr + t * 4);
    float s = vv.x + vv.y + vv.z + vv.w;
    #pragma unroll
    for (int o = 32; o > 0; o >>= 1) s += __shfl_down(s, o, 64);
    __shared__ float red[4];
    int lane = t & 63, wv = t >> 6;
    if (lane == 0) red[wv] = s;
    __syncthreads();
    float m = (red[0] + red[1] + red[2] + red[3]) * (1.0f / 784.0f);
    if (t < 200) {
        ushort4 hh = {0, 0, 0, 0}, ll = {0, 0, 0, 0};
        if (t < 196) {
            split_bf(vv.x - m, hh.x, ll.x);
            split_bf(vv.y - m, hh.y, ll.y);
            split_bf(vv.z - m, hh.z, ll.z);
            split_bf(vv.w - m, hh.w, ll.w);
        }
        *(ushort4*)&Xh[(size_t)row * 800 + t * 4] = hh;
        *(ushort4*)&Xl[(size_t)row * 800 + t * 4] = ll;
    }
}

// ---------- bf16x3 NT GEMM, 128x128 tile, BK=32, 256 thr ----------
// C[m][n] = sum_k A[m][k]*B[n][k] (all stored matrices symmetric, so NT == NN)
// MODE 0: TT (triangular grid, write C hi/lo + mirror)
// MODE 1: write M=C hi/lo and T=0.5(3I-C) hi/lo
// MODE 2: write T only
// MODE 3: cov (triangular): C*=cscale, write hi/lo + mirror, atomic trace of diag
template<int MODE>
__global__ __launch_bounds__(256) void gemm_bf3(
        const unsigned short* __restrict__ Ah, const unsigned short* __restrict__ Al,
        const unsigned short* __restrict__ Bh, const unsigned short* __restrict__ Bl,
        unsigned short* __restrict__ Ch, unsigned short* __restrict__ Cl,
        unsigned short* __restrict__ Th, unsigned short* __restrict__ Tl,
        float* __restrict__ tr, int K, int lda, float cscale) {
    constexpr bool TRI = (MODE == 0 || MODE == 3);
    __shared__ __align__(16) unsigned short lds[4 * 4096];   // Ahi|Alo|Bhi|Blo tiles [128][32]

    int bz = blockIdx.z;
    int by, bx;
    if (TRI) {
        int u = blockIdx.x;                // upper-triangle pairs of 4x4 tile grid
        if (u < 4)      { by = 0; bx = u; }
        else if (u < 7) { by = 1; bx = u - 3; }
        else if (u < 9) { by = 2; bx = u - 5; }
        else            { by = 3; bx = 3; }
    } else { by = blockIdx.y; bx = blockIdx.x; }

    size_t sAB = (size_t)512 * lda;
    size_t sC  = (size_t)512 * 512;
    const unsigned short* pAh = Ah + (size_t)bz * sAB;
    const unsigned short* pAl = Al + (size_t)bz * sAB;
    const unsigned short* pBh = Bh + (size_t)bz * sAB;
    const unsigned short* pBl = Bl + (size_t)bz * sAB;

    int tid = threadIdx.x;
    int w = tid >> 6, l = tid & 63;
    int row0A = by * 128, row0B = bx * 128;

    // staging: LDS slot S (16B units) = w*128 + i*64 + lane; row=S>>2, kslot g = (S&3)^((row>>1)&3)
    int S0 = w * 128 + l, S1 = S0 + 64;
    int r0 = S0 >> 2, g0 = (S0 & 3) ^ ((r0 >> 1) & 3);
    int r1 = S1 >> 2, g1 = (S1 & 3) ^ ((r1 >> 1) & 3);
    size_t offA0 = (size_t)(row0A + r0) * lda + g0 * 8;
    size_t offA1 = (size_t)(row0A + r1) * lda + g1 * 8;
    size_t offB0 = (size_t)(row0B + r0) * lda + g0 * 8;
    size_t offB1 = (size_t)(row0B + r1) * lda + g1 * 8;
    unsigned short* l0 = &lds[(w * 128) * 8];        // wave-uniform LDS bases
    unsigned short* l1 = &lds[(w * 128 + 64) * 8];

    f4 zero4 = {0.f, 0.f, 0.f, 0.f};
    f4 acc[4][4];
    #pragma unroll
    for (int i = 0; i < 4; ++i)
        #pragma unroll
        for (int j = 0; j < 4; ++j) acc[i][j] = zero4;

    int fr = l & 15, quad = l >> 4;
    int sw = quad ^ ((fr >> 1) & 3);                 // de-swizzle k-slot
    int wm = (w >> 1) * 64, wn = (w & 1) * 64;

    for (int k0 = 0; k0 < K; k0 += 32) {
        __syncthreads();
        async16(pAh + offA0 + k0, l0 + 0 * 4096);
        async16(pAh + offA1 + k0, l1 + 0 * 4096);
        async16(pAl + offA0 + k0, l0 + 1 * 4096);
        async16(pAl + offA1 + k0, l1 + 1 * 4096);
        async16(pBh + offB0 + k0, l0 + 2 * 4096);
        async16(pBh + offB1 + k0, l1 + 2 * 4096);
        async16(pBl + offB0 + k0, l0 + 3 * 4096);
        async16(pBl + offB1 + k0, l1 + 3 * 4096);
        __syncthreads();                              // implicit vmcnt(0) drain
        bf8 ah[4], alo[4], bh[4], blo[4];
        #pragma unroll
        for (int t = 0; t < 4; ++t) {
            int ro = wm + t * 16 + fr;
            int oa = (ro * 4 + sw) * 8;
            ah[t]  = *(const bf8*)&lds[0 * 4096 + oa];
            alo[t] = *(const bf8*)&lds[1 * 4096 + oa];
            int co = wn + t * 16 + fr;
            int ob = (co * 4 + sw) * 8;
            bh[t]  = *(const bf8*)&lds[2 * 4096 + ob];
            blo[t] = *(const bf8*)&lds[3 * 4096 + ob];
        }
        #pragma unroll
        for (int i = 0; i < 4; ++i)
            #pragma unroll
            for (int j = 0; j < 4; ++j) {
                acc[i][j] = __builtin_amdgcn_mfma_f32_16x16x32_bf16(ah[i],  bh[j],  acc[i][j], 0, 0, 0);
                acc[i][j] = __builtin_amdgcn_mfma_f32_16x16x32_bf16(ah[i],  blo[j], acc[i][j], 0, 0, 0);
                acc[i][j] = __builtin_amdgcn_mfma_f32_16x16x32_bf16(alo[i], bh[j],  acc[i][j], 0, 0, 0);
            }
    }

    unsigned short* qCh = (MODE != 2) ? Ch + (size_t)bz * sC : nullptr;
    unsigned short* qCl = (MODE != 2) ? Cl + (size_t)bz * sC : nullptr;
    unsigned short* qTh = (MODE == 1 || MODE == 2) ? Th + (size_t)bz * sC : nullptr;
    unsigned short* qTl = (MODE == 1 || MODE == 2) ? Tl + (size_t)bz * sC : nullptr;

    #pragma unroll
    for (int i = 0; i < 4; ++i) {
        int rb = row0A + wm + i * 16 + quad * 4;
        #pragma unroll
        for (int j = 0; j < 4; ++j) {
            int cc = row0B + wn + j * 16 + fr;
            #pragma unroll
            for (int r = 0; r < 4; ++r) {
                int row = rb + r;
                float vv = acc[i][j][r];
                if (MODE == 3) vv *= cscale;
                size_t idx = (size_t)row * 512 + cc;
                if (MODE == 0 || MODE == 1 || MODE == 3) {
                    unsigned short h, lo; split_bf(vv, h, lo);
                    qCh[idx] = h; qCl[idx] = lo;
                    if (TRI && bx != by) {                 // mirror tile (C symmetric)
                        size_t idT = (size_t)cc * 512 + row;
                        qCh[idT] = h; qCl[idT] = lo;
                    }
                }
                if (MODE == 3 && row == cc) atomicAdd(&tr[bz], vv);
                if (MODE == 1 || MODE == 2) {
                    float t = (row == cc) ? (1.5f - 0.5f * vv) : (-0.5f * vv);
                    unsigned short h, lo; split_bf(t, h, lo);
                    qTh[idx] = h; qTl[idx] = lo;
                }
            }
        }
    }
}

// ---------- An = cov/tr (in-place on hi/lo planes); T0 = 0.5(3I - An) ----------
__global__ __launch_bounds__(256) void prep(unsigned short* __restrict__ Mh, unsigned short* __restrict__ Ml,
        unsigned short* __restrict__ Th, unsigned short* __restrict__ Tl,
        const float* __restrict__ tr) {
    size_t i4 = ((size_t)blockIdx.x * 256 + threadIdx.x) * 4;   // 4 elems/thread
    int b = (int)(i4 >> 18);
    int rem = (int)(i4 & 262143);
    int row = rem >> 9, col = rem & 511;
    float invt = 1.0f / tr[b];
    ushort4 h = *(const ushort4*)&Mh[i4];
    ushort4 lo = *(const ushort4*)&Ml[i4];
    float a[4];
    a[0] = (bf2f(h.x) + bf2f(lo.x)) * invt;
    a[1] = (bf2f(h.y) + bf2f(lo.y)) * invt;
    a[2] = (bf2f(h.z) + bf2f(lo.z)) * invt;
    a[3] = (bf2f(h.w) + bf2f(lo.w)) * invt;
    ushort4 mh, ml, th, tl;
    unsigned short hh, ll;
    split_bf(a[0], mh.x, ml.x); split_bf(a[1], mh.y, ml.y);
    split_bf(a[2], mh.z, ml.z); split_bf(a[3], mh.w, ml.w);
    float t0 = (col + 0 == row) ? (1.5f - 0.5f * a[0]) : (-0.5f * a[0]);
    float t1 = (col + 1 == row) ? (1.5f - 0.5f * a[1]) : (-0.5f * a[1]);
    float t2 = (col + 2 == row) ? (1.5f - 0.5f * a[2]) : (-0.5f * a[2]);
    float t3 = (col + 3 == row) ? (1.5f - 0.5f * a[3]) : (-0.5f * a[3]);
    split_bf(t0, hh, ll); th.x = hh; tl.x = ll;
    split_bf(t1, hh, ll); th.y = hh; tl.y = ll;
    split_bf(t2, hh, ll); th.z = hh; tl.z = ll;
    split_bf(t3, hh, ll); th.w = hh; tl.w = ll;
    *(ushort4*)&Mh[i4] = mh; *(ushort4*)&Ml[i4] = ml;
    *(ushort4*)&Th[i4] = th; *(ushort4*)&Tl[i4] = tl;
}

// ---------- v <- v @ P (row-vector times matrix), hi/lo planes; ONES: v==1 ----------
template<int ONES>
__global__ __launch_bounds__(256) void vecmat_partial(
        const unsigned short* __restrict__ Ph, const unsigned short* __restrict__ Pl,
        const float* __restrict__ vin, float* __restrict__ part) {
    int b = blockIdx.x, ch = blockIdx.y;      // 8 row-chunks of 64
    size_t pb = (size_t)b * 512 * 512;
    int c2 = threadIdx.x * 2;
    float s0 = 0.f, s1 = 0.f;
    int r0 = ch * 64;
    for (int r = 0; r < 64; ++r) {
        float wgt = ONES ? 1.0f : vin[b * 512 + r0 + r];
        unsigned int hv = *(const unsigned int*)&Ph[pb + (size_t)(r0 + r) * 512 + c2];
        unsigned int lv = *(const unsigned int*)&Pl[pb + (size_t)(r0 + r) * 512 + c2];
        s0 += wgt * (bf2f((unsigned short)(hv & 0xffffu)) + bf2f((unsigned short)(lv & 0xffffu)));
        s1 += wgt * (bf2f((unsigned short)(hv >> 16)) + bf2f((unsigned short)(lv >> 16)));
    }
    float* pp = part + ((size_t)(b * 8 + ch)) * 512 + c2;
    pp[0] = s0; pp[1] = s1;
}

__global__ __launch_bounds__(256) void vecmat_reduce(const float* __restrict__ part,
                                                     float* __restrict__ v) {
    int b = blockIdx.x;
    for (int c = threadIdx.x; c < 512; c += 256) {
        float s = 0.f;
        #pragma unroll
        for (int j = 0; j < 8; ++j) s += part[((size_t)(b * 8 + j)) * 512 + c];
        v[b * 512 + c] = s;
    }
}

// ---------- out = x * v[ch]/512*sqrt(tr[b]) ----------
__global__ __launch_bounds__(256) void scale_x(const float* __restrict__ x,
        const float* __restrict__ v, const float* __restrict__ tr,
        float* __restrict__ out) {
    size_t i = (size_t)blockIdx.x * 256 + threadIdx.x;   // float4 index, exact grid
    size_t ch = i / 196;
    int b = (int)(ch >> 9);
    float sc = v[ch] * (1.0f / 512.0f) * sqrtf(tr[b]);
    float4 vv = ((const float4*)x)[i];
    vv.x *= sc; vv.y *= sc; vv.z *= sc; vv.w *= sc;
    ((float4*)out)[i] = vv;
}

extern "C" void kernel_launch(void* const* d_in, const int* in_sizes, int n_in,
                              void* d_out, int out_size, void* d_ws, size_t ws_size,
                              hipStream_t stream) {
    const float* x = (const float*)d_in[0];
    float* out = (float*)d_out;
    char* ws = (char*)d_ws;

    const size_t PLANE  = (size_t)32 * 512 * 512 * 2;   // 16,777,216 B per bf16 plane set
    const size_t XPLANE = (size_t)32 * 512 * 800 * 2;   // 26,214,400 B (padded Xc plane)

    float* tr   = (float*)(ws);
    float* v    = (float*)(ws + 1024);
    float* part = (float*)(ws + 1024 + 65536);
    char* big = ws + (1 << 20);
    unsigned short* Anh = (unsigned short*)(big);
    unsigned short* Anl = (unsigned short*)(big + PLANE);
    char* R0 = big + 2 * PLANE;
    // Xc planes (dead after gram) overlap T/TT planes
    unsigned short* Xh  = (unsigned short*)(R0);
    unsigned short* Xl  = (unsigned short*)(R0 + XPLANE);
    unsigned short* Th  = (unsigned short*)(R0);
    unsigned short* Tl  = (unsigned short*)(R0 + PLANE);
    unsigned short* TTh = (unsigned short*)(R0 + 2 * PLANE);
    unsigned short* TTl = (unsigned short*)(R0 + 3 * PLANE);
    size_t need = (1 << 20) + 8 * PLANE;                // ~135.3 MB
    unsigned short *Mbh, *Mbl;
    if (ws_size >= need) {
        Mbh = (unsigned short*)(R0 + 4 * PLANE);
        Mbl = (unsigned short*)(R0 + 5 * PLANE);
    } else {                                            // d_out as scratch (51.4 MB >= 33.5 MB)
        Mbh = (unsigned short*)out;
        Mbl = (unsigned short*)out + (size_t)32 * 512 * 512;
    }

    hipMemsetAsync(tr, 0, 128, stream);

    // 1) center + split to bf16 hi/lo, K padded to 800
    center_convert<<<32 * 512, 256, 0, stream>>>(x, Xh, Xl);
    // 2) cov = Xc@Xc^T/784 (triangular grid) + trace via atomics
    gemm_bf3<3><<<dim3(10, 1, 32), 256, 0, stream>>>(Xh, Xl, Xh, Xl, Anh, Anl,
                                                     nullptr, nullptr, tr, 800, 800, 1.0f / 784.0f);
    // 3) An = cov/tr (in place), T0 = 0.5(3I - An)
    prep<<<8192, 256, 0, stream>>>(Anh, Anl, Th, Tl, tr);
    // 4) v0 = colsum(An)
    vecmat_partial<1><<<dim3(32, 8), 256, 0, stream>>>(Anh, Anl, nullptr, part);
    vecmat_reduce<<<32, 256, 0, stream>>>(part, v);
    // 5) M/T recurrence: M_{k+1} = M_k @ T_k^2 ; T = 0.5(3I - M); v <- v@T_k
    const unsigned short* Msh = Anh; const unsigned short* Msl = Anl;
    unsigned short* Mdh = Mbh; unsigned short* Mdl = Mbl;
    for (int k = 0; k < 4; ++k) {
        vecmat_partial<0><<<dim3(32, 8), 256, 0, stream>>>(Th, Tl, v, part);
        vecmat_reduce<<<32, 256, 0, stream>>>(part, v);
        gemm_bf3<0><<<dim3(10, 1, 32), 256, 0, stream>>>(Th, Tl, Th, Tl, TTh, TTl,
                                                         nullptr, nullptr, nullptr, 512, 512, 1.0f);
        if (k < 3) {
            gemm_bf3<1><<<dim3(4, 4, 32), 256, 0, stream>>>(Msh, Msl, TTh, TTl, Mdh, Mdl,
                                                            Th, Tl, nullptr, 512, 512, 1.0f);
        } else {
            gemm_bf3<2><<<dim3(4, 4, 32), 256, 0, stream>>>(Msh, Msl, TTh, TTl, nullptr, nullptr,
                                                            Th, Tl, nullptr, 512, 512, 1.0f);
        }
        const unsigned short* th_ = Msh; const unsigned short* tl_ = Msl;
        Msh = Mdh; Msl = Mdl;
        Mdh = (unsigned short*)th_; Mdl = (unsigned short*)tl_;
    }
    // 6) v <- v@T_4 ; then out = x * v/512 * sqrt(tr)
    vecmat_partial<0><<<dim3(32, 8), 256, 0, stream>>>(Th, Tl, v, part);
    vecmat_reduce<<<32, 256, 0, stream>>>(part, v);
    scale_x<<<12544, 256, 0, stream>>>(x, v, tr, out);
}

// Round 3
// 548.975 us; speedup vs baseline: 2.7678x; 1.2816x over previous
//
#include <hip/hip_runtime.h>
#include <math.h>

typedef short bf8 __attribute__((ext_vector_type(8)));   // 8 bf16 = 4 VGPRs
typedef float f4 __attribute__((ext_vector_type(4)));

__device__ inline unsigned short f2bf(float f) {          // RNE f32 -> bf16
    unsigned int u = __float_as_uint(f);
    u = u + 0x7fffu + ((u >> 16) & 1u);
    return (unsigned short)(u >> 16);
}
__device__ inline float bf2f(unsigned short h) {
    return __uint_as_float(((unsigned int)h) << 16);
}
__device__ inline void split_bf(float v, unsigned short& h, unsigned short& l) {
    h = f2bf(v);
    l = f2bf(v - bf2f(h));
}
__device__ inline unsigned int packbf(unsigned short a, unsigned short b) {
    return (unsigned int)a | ((unsigned int)b << 16);
}
__device__ inline void async16(const void* g, void* l) {
    __builtin_amdgcn_global_load_lds(
        (const __attribute__((address_space(1))) unsigned int*)g,
        (__attribute__((address_space(3))) unsigned int*)l, 16, 0, 0);
}

// ---------- fuse row-mean + center + bf16 hi/lo split (K padded 784->800 with zeros) ----------
__global__ __launch_bounds__(256) void center_convert(const float* __restrict__ x,
        unsigned short* __restrict__ Xh, unsigned short* __restrict__ Xl) {
    int row = blockIdx.x;                       // b*512 + c
    const float* xr = x + (size_t)row * 784;
    int t = threadIdx.x;
    float4 vv = {0.f, 0.f, 0.f, 0.f};
    if (t < 196) vv = *(const float4*)(xr + t * 4);
    float s = vv.x + vv.y + vv.z + vv.w;
    #pragma unroll
    for (int o = 32; o > 0; o >>= 1) s += __shfl_down(s, o, 64);
    __shared__ float red[4];
    int lane = t & 63, wv = t >> 6;
    if (lane == 0) red[wv] = s;
    __syncthreads();
    float m = (red[0] + red[1] + red[2] + red[3]) * (1.0f / 784.0f);
    if (t < 200) {
        ushort4 hh = {0, 0, 0, 0}, ll = {0, 0, 0, 0};
        if (t < 196) {
            split_bf(vv.x - m, hh.x, ll.x);
            split_bf(vv.y - m, hh.y, ll.y);
            split_bf(vv.z - m, hh.z, ll.z);
            split_bf(vv.w - m, hh.w, ll.w);
        }
        *(ushort4*)&Xh[(size_t)row * 800 + t * 4] = hh;
        *(ushort4*)&Xl[(size_t)row * 800 + t * 4] = ll;
    }
}

// ---------- triangular bf16x3 NT GEMM, 128x128 tile, BK=32, double-buffered LDS ----------
// C[m][n] = sum_k A[m][k]*B[n][k]; all inputs/outputs symmetric -> tri grid + transposed mirror.
// MODE 0: C = A@B^T               (S = M^2)
// MODE 1: C = 0.25*(9M - 6S + G), G = A@B^T (A=M, B=S)
// MODE 3: C = (A@B^T)*cscale     (covariance)
template<int MODE>
__global__ __launch_bounds__(256) void gemm_tri(
        const unsigned short* __restrict__ Ah, const unsigned short* __restrict__ Al,
        const unsigned short* __restrict__ Bh, const unsigned short* __restrict__ Bl,
        const unsigned short* __restrict__ Mh, const unsigned short* __restrict__ Ml,
        const unsigned short* __restrict__ Sh, const unsigned short* __restrict__ Sl,
        unsigned short* __restrict__ Ch, unsigned short* __restrict__ Cl,
        int K, int lda, float cscale) {
    __shared__ __align__(16) char smem[66048];               // 2x32768 staging | 128*129 f32 epi
    unsigned short* stage = (unsigned short*)smem;
    float* tilef = (float*)smem;

    int bz = blockIdx.z;
    int u = blockIdx.x, by, bx;
    if (u < 4)      { by = 0; bx = u; }
    else if (u < 7) { by = 1; bx = u - 3; }
    else if (u < 9) { by = 2; bx = u - 5; }
    else            { by = 3; bx = 3; }

    size_t sAB = (size_t)512 * lda;
    size_t sC  = (size_t)512 * 512;
    const unsigned short* pAh = Ah + (size_t)bz * sAB;
    const unsigned short* pAl = Al + (size_t)bz * sAB;
    const unsigned short* pBh = Bh + (size_t)bz * sAB;
    const unsigned short* pBl = Bl + (size_t)bz * sAB;

    int tid = threadIdx.x;
    int w = tid >> 6, l = tid & 63;
    int rb0 = by * 128, cb0 = bx * 128;

    // staging slots (16B units): S = w*128 + i*64 + l; row=S>>2, k-slot g = (S&3)^((row>>1)&3)
    int S0 = w * 128 + l, S1 = S0 + 64;
    int r0 = S0 >> 2, g0 = (S0 & 3) ^ ((r0 >> 1) & 3);
    int r1 = S1 >> 2, g1 = (S1 & 3) ^ ((r1 >> 1) & 3);
    size_t offA0 = (size_t)(rb0 + r0) * lda + g0 * 8;
    size_t offA1 = (size_t)(rb0 + r1) * lda + g1 * 8;
    size_t offB0 = (size_t)(cb0 + r0) * lda + g0 * 8;
    size_t offB1 = (size_t)(cb0 + r1) * lda + g1 * 8;
    int L0 = (w * 128) * 8, L1 = (w * 128 + 64) * 8;        // wave-uniform LDS short-offsets

    f4 zero4 = {0.f, 0.f, 0.f, 0.f};
    f4 acc[4][4];
    #pragma unroll
    for (int i = 0; i < 4; ++i)
        #pragma unroll
        for (int j = 0; j < 4; ++j) acc[i][j] = zero4;

    int fr = l & 15, quad = l >> 4;
    int sw = quad ^ ((fr >> 1) & 3);
    int wm = (w >> 1) * 64, wn = (w & 1) * 64;
    int NK = K >> 5;

    // prologue: stage chunk 0 into buf 0
    {
        unsigned short* sb = stage;
        async16(pAh + offA0, sb + 0 * 4096 + L0); async16(pAh + offA1, sb + 0 * 4096 + L1);
        async16(pAl + offA0, sb + 1 * 4096 + L0); async16(pAl + offA1, sb + 1 * 4096 + L1);
        async16(pBh + offB0, sb + 2 * 4096 + L0); async16(pBh + offB1, sb + 2 * 4096 + L1);
        async16(pBl + offB0, sb + 3 * 4096 + L0); async16(pBl + offB1, sb + 3 * 4096 + L1);
    }
    for (int ki = 0; ki < NK; ++ki) {
        __syncthreads();                         // drains buf[ki&1] loads (vmcnt0 + barrier)
        if (ki + 1 < NK) {                       // prefetch next chunk into other buffer
            int k0 = (ki + 1) << 5;
            unsigned short* sb = stage + ((ki + 1) & 1) * 16384;
            async16(pAh + offA0 + k0, sb + 0 * 4096 + L0); async16(pAh + offA1 + k0, sb + 0 * 4096 + L1);
            async16(pAl + offA0 + k0, sb + 1 * 4096 + L0); async16(pAl + offA1 + k0, sb + 1 * 4096 + L1);
            async16(pBh + offB0 + k0, sb + 2 * 4096 + L0); async16(pBh + offB1 + k0, sb + 2 * 4096 + L1);
            async16(pBl + offB0 + k0, sb + 3 * 4096 + L0); async16(pBl + offB1 + k0, sb + 3 * 4096 + L1);
        }
        const unsigned short* sb = stage + (ki & 1) * 16384;
        bf8 ah[4], alo[4], bh[4], blo[4];
        #pragma unroll
        for (int t = 0; t < 4; ++t) {
            int oa = ((wm + t * 16 + fr) * 4 + sw) * 8;
            ah[t]  = *(const bf8*)&sb[0 * 4096 + oa];
            alo[t] = *(const bf8*)&sb[1 * 4096 + oa];
            int ob = ((wn + t * 16 + fr) * 4 + sw) * 8;
            bh[t]  = *(const bf8*)&sb[2 * 4096 + ob];
            blo[t] = *(const bf8*)&sb[3 * 4096 + ob];
        }
        #pragma unroll
        for (int i = 0; i < 4; ++i)
            #pragma unroll
            for (int j = 0; j < 4; ++j) {
                acc[i][j] = __builtin_amdgcn_mfma_f32_16x16x32_bf16(ah[i],  bh[j],  acc[i][j], 0, 0, 0);
                acc[i][j] = __builtin_amdgcn_mfma_f32_16x16x32_bf16(ah[i],  blo[j], acc[i][j], 0, 0, 0);
                acc[i][j] = __builtin_amdgcn_mfma_f32_16x16x32_bf16(alo[i], bh[j],  acc[i][j], 0, 0, 0);
            }
    }

    // ---- epilogue: acc -> f32 LDS tile [128][129] ----
    __syncthreads();
    #pragma unroll
    for (int i = 0; i < 4; ++i) {
        int rloc = wm + i * 16 + quad * 4;
        #pragma unroll
        for (int j = 0; j < 4; ++j) {
            int cloc = wn + j * 16 + fr;
            #pragma unroll
            for (int r = 0; r < 4; ++r) tilef[(rloc + r) * 129 + cloc] = acc[i][j][r];
        }
    }
    __syncthreads();

    unsigned short* qCh = Ch + (size_t)bz * sC;
    unsigned short* qCl = Cl + (size_t)bz * sC;
    const unsigned short* qMh = (MODE == 1) ? Mh + (size_t)bz * sC : nullptr;
    const unsigned short* qMl = (MODE == 1) ? Ml + (size_t)bz * sC : nullptr;
    const unsigned short* qSh = (MODE == 1) ? Sh + (size_t)bz * sC : nullptr;
    const unsigned short* qSl = (MODE == 1) ? Sl + (size_t)bz * sC : nullptr;

    int lr = tid >> 4, lc0 = (tid & 15) * 8;
    // straight pass: rows rb0+lr+16p, cols cb0+lc0..+7 (coalesced dwordx4 stores)
    #pragma unroll
    for (int p = 0; p < 8; ++p) {
        int row = lr + p * 16;
        int grow = rb0 + row, gcol = cb0 + lc0;
        float vv[8];
        #pragma unroll
        for (int k = 0; k < 8; ++k) vv[k] = tilef[row * 129 + lc0 + k];
        size_t gaddr = (size_t)grow * 512 + gcol;
        if (MODE == 3) {
            #pragma unroll
            for (int k = 0; k < 8; ++k) vv[k] *= cscale;
        }
        if (MODE == 1) {
            uint4 mh = *(const uint4*)&qMh[gaddr], ml = *(const uint4*)&qMl[gaddr];
            uint4 sh = *(const uint4*)&qSh[gaddr], sl = *(const uint4*)&qSl[gaddr];
            const unsigned int* mhp = (const unsigned int*)&mh; const unsigned int* mlp = (const unsigned int*)&ml;
            const unsigned int* shp = (const unsigned int*)&sh; const unsigned int* slp = (const unsigned int*)&sl;
            #pragma unroll
            for (int k = 0; k < 8; ++k) {
                unsigned int hm = mhp[k >> 1], lm = mlp[k >> 1], hs = shp[k >> 1], ls = slp[k >> 1];
                unsigned short mh_ = (k & 1) ? (hm >> 16) : (hm & 0xffffu);
                unsigned short ml_ = (k & 1) ? (lm >> 16) : (lm & 0xffffu);
                unsigned short sh_ = (k & 1) ? (hs >> 16) : (hs & 0xffffu);
                unsigned short sl_ = (k & 1) ? (ls >> 16) : (ls & 0xffffu);
                float mval = bf2f(mh_) + bf2f(ml_);
                float sval = bf2f(sh_) + bf2f(sl_);
                vv[k] = 0.25f * (9.0f * mval - 6.0f * sval + vv[k]);
            }
        }
        unsigned short h[8], lo[8];
        #pragma unroll
        for (int k = 0; k < 8; ++k) split_bf(vv[k], h[k], lo[k]);
        uint4 uh, ul;
        uh.x = packbf(h[0], h[1]); uh.y = packbf(h[2], h[3]); uh.z = packbf(h[4], h[5]); uh.w = packbf(h[6], h[7]);
        ul.x = packbf(lo[0], lo[1]); ul.y = packbf(lo[2], lo[3]); ul.z = packbf(lo[4], lo[5]); ul.w = packbf(lo[6], lo[7]);
        *(uint4*)&qCh[gaddr] = uh;
        *(uint4*)&qCl[gaddr] = ul;
    }
    // mirror pass (transpose via LDS; output symmetric)
    if (bx != by) {
        #pragma unroll
        for (int p = 0; p < 8; ++p) {
            int mr = lr + p * 16;                 // mirror-local row -> global row cb0+mr
            int grow = cb0 + mr, gcol = rb0 + lc0;
            float vv[8];
            #pragma unroll
            for (int k = 0; k < 8; ++k) vv[k] = tilef[(lc0 + k) * 129 + mr];
            size_t gaddr = (size_t)grow * 512 + gcol;
            if (MODE == 3) {
                #pragma unroll
                for (int k = 0; k < 8; ++k) vv[k] *= cscale;
            }
            if (MODE == 1) {
                uint4 mh = *(const uint4*)&qMh[gaddr], ml = *(const uint4*)&qMl[gaddr];
                uint4 sh = *(const uint4*)&qSh[gaddr], sl = *(const uint4*)&qSl[gaddr];
                const unsigned int* mhp = (const unsigned int*)&mh; const unsigned int* mlp = (const unsigned int*)&ml;
                const unsigned int* shp = (const unsigned int*)&sh; const unsigned int* slp = (const unsigned int*)&sl;
                #pragma unroll
                for (int k = 0; k < 8; ++k) {
                    unsigned int hm = mhp[k >> 1], lm = mlp[k >> 1], hs = shp[k >> 1], ls = slp[k >> 1];
                    unsigned short mh_ = (k & 1) ? (hm >> 16) : (hm & 0xffffu);
                    unsigned short ml_ = (k & 1) ? (lm >> 16) : (lm & 0xffffu);
                    unsigned short sh_ = (k & 1) ? (hs >> 16) : (hs & 0xffffu);
                    unsigned short sl_ = (k & 1) ? (ls >> 16) : (ls & 0xffffu);
                    float mval = bf2f(mh_) + bf2f(ml_);
                    float sval = bf2f(sh_) + bf2f(sl_);
                    vv[k] = 0.25f * (9.0f * mval - 6.0f * sval + vv[k]);
                }
            }
            unsigned short h[8], lo[8];
            #pragma unroll
            for (int k = 0; k < 8; ++k) split_bf(vv[k], h[k], lo[k]);
            uint4 uh, ul;
            uh.x = packbf(h[0], h[1]); uh.y = packbf(h[2], h[3]); uh.z = packbf(h[4], h[5]); uh.w = packbf(h[6], h[7]);
            ul.x = packbf(lo[0], lo[1]); ul.y = packbf(lo[2], lo[3]); ul.z = packbf(lo[4], lo[5]); ul.w = packbf(lo[6], lo[7]);
            *(uint4*)&qCh[gaddr] = uh;
            *(uint4*)&qCl[gaddr] = ul;
        }
    }
}

// ---------- trace of cov per batch ----------
__global__ __launch_bounds__(512) void trace_kernel(const unsigned short* __restrict__ Ah,
        const unsigned short* __restrict__ Al, float* __restrict__ tr) {
    int b = blockIdx.x, t = threadIdx.x;
    size_t d = (size_t)b * 512 * 512 + (size_t)t * 512 + t;
    float s = bf2f(Ah[d]) + bf2f(Al[d]);
    #pragma unroll
    for (int o = 32; o > 0; o >>= 1) s += __shfl_down(s, o, 64);
    __shared__ float red[8];
    int lane = t & 63, wv = t >> 6;
    if (lane == 0) red[wv] = s;
    __syncthreads();
    if (t == 0) {
        float tt = 0.f;
        #pragma unroll
        for (int i = 0; i < 8; ++i) tt += red[i];
        tr[b] = tt;
    }
}

// ---------- An = cov/tr (in place on hi/lo planes) ----------
__global__ __launch_bounds__(256) void prep(unsigned short* __restrict__ Mh,
        unsigned short* __restrict__ Ml, const float* __restrict__ tr) {
    size_t i4 = ((size_t)blockIdx.x * 256 + threadIdx.x) * 4;
    int b = (int)(i4 >> 18);
    float invt = 1.0f / tr[b];
    ushort4 h = *(const ushort4*)&Mh[i4];
    ushort4 lo = *(const ushort4*)&Ml[i4];
    ushort4 mh, ml;
    split_bf((bf2f(h.x) + bf2f(lo.x)) * invt, mh.x, ml.x);
    split_bf((bf2f(h.y) + bf2f(lo.y)) * invt, mh.y, ml.y);
    split_bf((bf2f(h.z) + bf2f(lo.z)) * invt, mh.z, ml.z);
    split_bf((bf2f(h.w) + bf2f(lo.w)) * invt, mh.w, ml.w);
    *(ushort4*)&Mh[i4] = mh; *(ushort4*)&Ml[i4] = ml;
}

// ---------- partials of v @ M (row-vector x matrix); ONES: v == 1 ----------
template<int ONES>
__global__ __launch_bounds__(256) void vec_partial(
        const unsigned short* __restrict__ Ph, const unsigned short* __restrict__ Pl,
        const float* __restrict__ vin, float* __restrict__ part) {
    int b = blockIdx.x, ch = blockIdx.y;
    size_t pb = (size_t)b * 512 * 512;
    int c2 = threadIdx.x * 2;
    float s0 = 0.f, s1 = 0.f;
    int r0 = ch * 64;
    for (int r = 0; r < 64; ++r) {
        float wgt = ONES ? 1.0f : vin[b * 512 + r0 + r];
        unsigned int hv = *(const unsigned int*)&Ph[pb + (size_t)(r0 + r) * 512 + c2];
        unsigned int lv = *(const unsigned int*)&Pl[pb + (size_t)(r0 + r) * 512 + c2];
        s0 += wgt * (bf2f((unsigned short)(hv & 0xffffu)) + bf2f((unsigned short)(lv & 0xffffu)));
        s1 += wgt * (bf2f((unsigned short)(hv >> 16)) + bf2f((unsigned short)(lv >> 16)));
    }
    float* pp = part + ((size_t)(b * 8 + ch)) * 512 + c2;
    pp[0] = s0; pp[1] = s1;
}

// PLAIN: v = sum(parts)  |  TSTEP: v = 1.5*v - 0.5*sum(parts)
template<int TSTEP>
__global__ __launch_bounds__(256) void vec_reduce(const float* __restrict__ part,
                                                  float* __restrict__ v) {
    int b = blockIdx.x;
    for (int c = threadIdx.x; c < 512; c += 256) {
        float s = 0.f;
        #pragma unroll
        for (int j = 0; j < 8; ++j) s += part[((size_t)(b * 8 + j)) * 512 + c];
        if (TSTEP) v[b * 512 + c] = 1.5f * v[b * 512 + c] - 0.5f * s;
        else       v[b * 512 + c] = s;
    }
}

// ---------- out = x * v[ch]/512*sqrt(tr[b]) ----------
__global__ __launch_bounds__(256) void scale_x(const float* __restrict__ x,
        const float* __restrict__ v, const float* __restrict__ tr,
        float* __restrict__ out) {
    size_t i = (size_t)blockIdx.x * 256 + threadIdx.x;
    size_t ch = i / 196;
    int b = (int)(ch >> 9);
    float sc = v[ch] * (1.0f / 512.0f) * sqrtf(tr[b]);
    float4 vv = ((const float4*)x)[i];
    vv.x *= sc; vv.y *= sc; vv.z *= sc; vv.w *= sc;
    ((float4*)out)[i] = vv;
}

extern "C" void kernel_launch(void* const* d_in, const int* in_sizes, int n_in,
                              void* d_out, int out_size, void* d_ws, size_t ws_size,
                              hipStream_t stream) {
    const float* x = (const float*)d_in[0];
    float* out = (float*)d_out;
    char* ws = (char*)d_ws;

    const size_t PLANE  = (size_t)32 * 512 * 512 * 2;   // 16.78 MB per bf16 plane
    const size_t XPLANE = (size_t)32 * 512 * 800 * 2;   // 26.21 MB padded Xc plane

    float* tr   = (float*)(ws);                          // 32 f
    float* v    = (float*)(ws + 4096);                   // 32*512 f
    float* part = (float*)(ws + (128 << 10));            // 32*8*512 f
    char* big = ws + (1 << 20);
    unsigned short* Ah = (unsigned short*)(big);                 // An / M ping
    unsigned short* Al = (unsigned short*)(big + PLANE);
    char* R0 = big + 2 * PLANE;
    unsigned short* Xh = (unsigned short*)(R0);                  // dead after cov
    unsigned short* Xl = (unsigned short*)(R0 + XPLANE);
    unsigned short* Sh = (unsigned short*)(R0);                  // S = M^2 (overlaps X)
    unsigned short* Sl = (unsigned short*)(R0 + PLANE);
    size_t need = (1 << 20) + 2 * PLANE + 2 * XPLANE + 2 * PLANE;
    unsigned short *Bh, *Bl;                                      // M pong
    if (ws_size >= need) {
        Bh = (unsigned short*)(R0 + 2 * XPLANE);
        Bl = (unsigned short*)(R0 + 2 * XPLANE + PLANE);
    } else {                                              // d_out scratch (51.4 MB >= 33.5 MB)
        Bh = (unsigned short*)out;
        Bl = (unsigned short*)out + (size_t)32 * 512 * 512;
    }

    dim3 gtri(10, 1, 32);

    // 1) center + split
    center_convert<<<32 * 512, 256, 0, stream>>>(x, Xh, Xl);
    // 2) cov = Xc@Xc^T/784 (tri) -> A planes
    gemm_tri<3><<<gtri, 256, 0, stream>>>(Xh, Xl, Xh, Xl, nullptr, nullptr, nullptr, nullptr,
                                          Ah, Al, 800, 800, 1.0f / 784.0f);
    // 3) trace, then An = cov/tr
    trace_kernel<<<32, 512, 0, stream>>>(Ah, Al, tr);
    prep<<<8192, 256, 0, stream>>>(Ah, Al, tr);
    // 4) v = colsum(An); v <- 1.5v - 0.5 v@M_0
    vec_partial<1><<<dim3(32, 8), 256, 0, stream>>>(Ah, Al, nullptr, part);
    vec_reduce<0><<<32, 256, 0, stream>>>(part, v);
    vec_partial<0><<<dim3(32, 8), 256, 0, stream>>>(Ah, Al, v, part);
    vec_reduce<1><<<32, 256, 0, stream>>>(part, v);
    // 5) 4 iterations: S = M^2 ; M' = 0.25(9M - 6S + M@S) ; v <- 1.5v - 0.5 v@M'
    unsigned short *Mh_ = Ah, *Ml_ = Al, *Nh = Bh, *Nl = Bl;
    for (int j = 0; j < 4; ++j) {
        gemm_tri<0><<<gtri, 256, 0, stream>>>(Mh_, Ml_, Mh_, Ml_, nullptr, nullptr, nullptr, nullptr,
                                              Sh, Sl, 512, 512, 1.0f);
        gemm_tri<1><<<gtri, 256, 0, stream>>>(Mh_, Ml_, Sh, Sl, Mh_, Ml_, Sh, Sl,
                                              Nh, Nl, 512, 512, 1.0f);
        vec_partial<0><<<dim3(32, 8), 256, 0, stream>>>(Nh, Nl, v, part);
        vec_reduce<1><<<32, 256, 0, stream>>>(part, v);
        unsigned short* t1 = Mh_; Mh_ = Nh; Nh = t1;
        unsigned short* t2 = Ml_; Ml_ = Nl; Nl = t2;
    }
    // 6) out = x * v/512 * sqrt(tr)
    scale_x<<<12544, 256, 0, stream>>>(x, v, tr, out);
}

// Round 4
// 505.808 us; speedup vs baseline: 3.0040x; 1.0853x over previous
//
#include <hip/hip_runtime.h>
#include <math.h>

typedef short bf8 __attribute__((ext_vector_type(8)));   // 8 bf16 = 4 VGPRs
typedef float f4 __attribute__((ext_vector_type(4)));

__device__ inline unsigned short f2bf(float f) {          // RNE f32 -> bf16
    unsigned int u = __float_as_uint(f);
    u = u + 0x7fffu + ((u >> 16) & 1u);
    return (unsigned short)(u >> 16);
}
__device__ inline float bf2f(unsigned short h) {
    return __uint_as_float(((unsigned int)h) << 16);
}
__device__ inline void split_bf(float v, unsigned short& h, unsigned short& l) {
    h = f2bf(v);
    l = f2bf(v - bf2f(h));
}
__device__ inline unsigned int packbf(unsigned short a, unsigned short b) {
    return (unsigned int)a | ((unsigned int)b << 16);
}
__device__ inline void async16(const void* g, void* l) {
    __builtin_amdgcn_global_load_lds(
        (const __attribute__((address_space(1))) unsigned int*)g,
        (__attribute__((address_space(3))) unsigned int*)l, 16, 0, 0);
}

// ---------- fuse row-mean + center + bf16 hi/lo split (K padded 784->800 with zeros) ----------
__global__ __launch_bounds__(256) void center_convert(const float* __restrict__ x,
        unsigned short* __restrict__ Xh, unsigned short* __restrict__ Xl) {
    int row = blockIdx.x;                       // b*512 + c
    const float* xr = x + (size_t)row * 784;
    int t = threadIdx.x;
    float4 vv = {0.f, 0.f, 0.f, 0.f};
    if (t < 196) vv = *(const float4*)(xr + t * 4);
    float s = vv.x + vv.y + vv.z + vv.w;
    #pragma unroll
    for (int o = 32; o > 0; o >>= 1) s += __shfl_down(s, o, 64);
    __shared__ float red[4];
    int lane = t & 63, wv = t >> 6;
    if (lane == 0) red[wv] = s;
    __syncthreads();
    float m = (red[0] + red[1] + red[2] + red[3]) * (1.0f / 784.0f);
    if (t < 200) {
        ushort4 hh = {0, 0, 0, 0}, ll = {0, 0, 0, 0};
        if (t < 196) {
            split_bf(vv.x - m, hh.x, ll.x);
            split_bf(vv.y - m, hh.y, ll.y);
            split_bf(vv.z - m, hh.z, ll.z);
            split_bf(vv.w - m, hh.w, ll.w);
        }
        *(ushort4*)&Xh[(size_t)row * 800 + t * 4] = hh;
        *(ushort4*)&Xl[(size_t)row * 800 + t * 4] = ll;
    }
}

// ---------- triangular bf16x3 NT GEMM, 128x128 tile, BK=32, dbuf LDS, XCD-affine grid ----------
// bid = u*32 + bz  (bz fastest => batch bz pinned to XCD bz%8 for L2 reuse)
// MODE 0: C = A@B (S = M^2); ITER0: C *= invtr^2, CSUM=1 -> colsum(S0)
// MODE 1: C = 0.25(9*M*sc - 6*S + (A@B)*sc), sc = ITER0? invtr : 1; CSUM=2 -> vacc += vin.C
// MODE 3: C = (A@B)*cscale (cov); trace->tr atomics; CSUM=1 -> colsum(cov)
template<int MODE, int CSUM, int ITER0>
__global__ __launch_bounds__(256) void gemm_tri(
        const unsigned short* __restrict__ Ah, const unsigned short* __restrict__ Al,
        const unsigned short* __restrict__ Bh, const unsigned short* __restrict__ Bl,
        const unsigned short* __restrict__ Mh, const unsigned short* __restrict__ Ml,
        const unsigned short* __restrict__ Sh, const unsigned short* __restrict__ Sl,
        unsigned short* __restrict__ Ch, unsigned short* __restrict__ Cl,
        float* __restrict__ trp, float* __restrict__ csum, const float* __restrict__ vin,
        int K, int lda, float cscale) {
    __shared__ __align__(16) char smem[74240];   // 2x32768 staging | 128*129 f32 epi + colred
    unsigned short* stage = (unsigned short*)smem;
    float* tilef  = (float*)smem;
    float* colred = (float*)(smem + 66048);      // [16][128]

    int bid = blockIdx.x;
    int bz = bid & 31;
    int u = bid >> 5, by, bx;
    if (u < 4)      { by = 0; bx = u; }
    else if (u < 7) { by = 1; bx = u - 3; }
    else if (u < 9) { by = 2; bx = u - 5; }
    else            { by = 3; bx = 3; }

    size_t sAB = (size_t)512 * lda;
    size_t sC  = (size_t)512 * 512;
    const unsigned short* pAh = Ah + (size_t)bz * sAB;
    const unsigned short* pAl = Al + (size_t)bz * sAB;
    const unsigned short* pBh = Bh + (size_t)bz * sAB;
    const unsigned short* pBl = Bl + (size_t)bz * sAB;

    int tid = threadIdx.x;
    int w = tid >> 6, l = tid & 63;
    int rb0 = by * 128, cb0 = bx * 128;

    // staging slots (16B units): S = w*128 + i*64 + l; row=S>>2, k-slot g = (S&3)^((row>>1)&3)
    int S0 = w * 128 + l, S1 = S0 + 64;
    int r0 = S0 >> 2, g0 = (S0 & 3) ^ ((r0 >> 1) & 3);
    int r1 = S1 >> 2, g1 = (S1 & 3) ^ ((r1 >> 1) & 3);
    size_t offA0 = (size_t)(rb0 + r0) * lda + g0 * 8;
    size_t offA1 = (size_t)(rb0 + r1) * lda + g1 * 8;
    size_t offB0 = (size_t)(cb0 + r0) * lda + g0 * 8;
    size_t offB1 = (size_t)(cb0 + r1) * lda + g1 * 8;
    int L0 = (w * 128) * 8, L1 = (w * 128 + 64) * 8;

    f4 zero4 = {0.f, 0.f, 0.f, 0.f};
    f4 acc[4][4];
    #pragma unroll
    for (int i = 0; i < 4; ++i)
        #pragma unroll
        for (int j = 0; j < 4; ++j) acc[i][j] = zero4;

    int fr = l & 15, quad = l >> 4;
    int sw = quad ^ ((fr >> 1) & 3);
    int wm = (w >> 1) * 64, wn = (w & 1) * 64;
    int NK = K >> 5;

    {   // prologue: stage chunk 0 into buf 0
        unsigned short* sb = stage;
        async16(pAh + offA0, sb + 0 * 4096 + L0); async16(pAh + offA1, sb + 0 * 4096 + L1);
        async16(pAl + offA0, sb + 1 * 4096 + L0); async16(pAl + offA1, sb + 1 * 4096 + L1);
        async16(pBh + offB0, sb + 2 * 4096 + L0); async16(pBh + offB1, sb + 2 * 4096 + L1);
        async16(pBl + offB0, sb + 3 * 4096 + L0); async16(pBl + offB1, sb + 3 * 4096 + L1);
    }
    for (int ki = 0; ki < NK; ++ki) {
        __syncthreads();                         // drains buf[ki&1] (vmcnt0 + barrier)
        if (ki + 1 < NK) {
            int k0 = (ki + 1) << 5;
            unsigned short* sb = stage + ((ki + 1) & 1) * 16384;
            async16(pAh + offA0 + k0, sb + 0 * 4096 + L0); async16(pAh + offA1 + k0, sb + 0 * 4096 + L1);
            async16(pAl + offA0 + k0, sb + 1 * 4096 + L0); async16(pAl + offA1 + k0, sb + 1 * 4096 + L1);
            async16(pBh + offB0 + k0, sb + 2 * 4096 + L0); async16(pBh + offB1 + k0, sb + 2 * 4096 + L1);
            async16(pBl + offB0 + k0, sb + 3 * 4096 + L0); async16(pBl + offB1 + k0, sb + 3 * 4096 + L1);
        }
        const unsigned short* sb = stage + (ki & 1) * 16384;
        bf8 ah[4], alo[4], bh[4], blo[4];
        #pragma unroll
        for (int t = 0; t < 4; ++t) {
            int oa = ((wm + t * 16 + fr) * 4 + sw) * 8;
            ah[t]  = *(const bf8*)&sb[0 * 4096 + oa];
            alo[t] = *(const bf8*)&sb[1 * 4096 + oa];
            int ob = ((wn + t * 16 + fr) * 4 + sw) * 8;
            bh[t]  = *(const bf8*)&sb[2 * 4096 + ob];
            blo[t] = *(const bf8*)&sb[3 * 4096 + ob];
        }
        #pragma unroll
        for (int i = 0; i < 4; ++i)
            #pragma unroll
            for (int j = 0; j < 4; ++j) {
                acc[i][j] = __builtin_amdgcn_mfma_f32_16x16x32_bf16(ah[i],  bh[j],  acc[i][j], 0, 0, 0);
                acc[i][j] = __builtin_amdgcn_mfma_f32_16x16x32_bf16(ah[i],  blo[j], acc[i][j], 0, 0, 0);
                acc[i][j] = __builtin_amdgcn_mfma_f32_16x16x32_bf16(alo[i], bh[j],  acc[i][j], 0, 0, 0);
            }
    }

    // ---- epilogue: acc -> f32 LDS tile [128][129] ----
    __syncthreads();
    #pragma unroll
    for (int i = 0; i < 4; ++i) {
        int rloc = wm + i * 16 + quad * 4;
        #pragma unroll
        for (int j = 0; j < 4; ++j) {
            int cloc = wn + j * 16 + fr;
            #pragma unroll
            for (int r = 0; r < 4; ++r) tilef[(rloc + r) * 129 + cloc] = acc[i][j][r];
        }
    }
    __syncthreads();

    float invtr_e = 1.0f;
    if ((MODE == 0 || MODE == 1) && ITER0) invtr_e = 1.0f / trp[bz];
    const float sc_g = (MODE == 3) ? cscale
                      : (MODE == 0 ? (ITER0 ? invtr_e * invtr_e : 1.0f)
                                   : (ITER0 ? invtr_e : 1.0f));

    unsigned short* qCh = Ch + (size_t)bz * sC;
    unsigned short* qCl = Cl + (size_t)bz * sC;
    const unsigned short* qMh = (MODE == 1) ? Mh + (size_t)bz * sC : nullptr;
    const unsigned short* qMl = (MODE == 1) ? Ml + (size_t)bz * sC : nullptr;
    const unsigned short* qSh = (MODE == 1) ? Sh + (size_t)bz * sC : nullptr;
    const unsigned short* qSl = (MODE == 1) ? Sl + (size_t)bz * sC : nullptr;

    int lr = tid >> 4, lc0 = (tid & 15) * 8;
    int npass = (bx != by) ? 2 : 1;
    for (int pass = 0; pass < npass; ++pass) {
        int gr0 = pass ? cb0 : rb0;
        int gc0 = pass ? rb0 : cb0;
        float cp[8] = {0.f, 0.f, 0.f, 0.f, 0.f, 0.f, 0.f, 0.f};
        #pragma unroll
        for (int p = 0; p < 8; ++p) {
            int row = lr + p * 16;
            int grow = gr0 + row, gcol = gc0 + lc0;
            float vv[8];
            #pragma unroll
            for (int k = 0; k < 8; ++k)
                vv[k] = pass ? tilef[(lc0 + k) * 129 + row] : tilef[row * 129 + lc0 + k];
            size_t gaddr = (size_t)grow * 512 + gcol;
            if (MODE == 3 || MODE == 0) {
                #pragma unroll
                for (int k = 0; k < 8; ++k) vv[k] *= sc_g;
            }
            if (MODE == 1) {
                uint4 mh = *(const uint4*)&qMh[gaddr], ml = *(const uint4*)&qMl[gaddr];
                uint4 sh = *(const uint4*)&qSh[gaddr], sl = *(const uint4*)&qSl[gaddr];
                const unsigned int* mhp = (const unsigned int*)&mh; const unsigned int* mlp = (const unsigned int*)&ml;
                const unsigned int* shp = (const unsigned int*)&sh; const unsigned int* slp = (const unsigned int*)&sl;
                #pragma unroll
                for (int k = 0; k < 8; ++k) {
                    unsigned int hm = mhp[k >> 1], lm = mlp[k >> 1], hs = shp[k >> 1], ls = slp[k >> 1];
                    float mval = bf2f((unsigned short)((k & 1) ? (hm >> 16) : (hm & 0xffffu)))
                               + bf2f((unsigned short)((k & 1) ? (lm >> 16) : (lm & 0xffffu)));
                    float sval = bf2f((unsigned short)((k & 1) ? (hs >> 16) : (hs & 0xffffu)))
                               + bf2f((unsigned short)((k & 1) ? (ls >> 16) : (ls & 0xffffu)));
                    vv[k] = 0.25f * (9.0f * mval * sc_g - 6.0f * sval + vv[k] * sc_g);
                }
            }
            // store bf16 hi/lo
            unsigned short h[8], lo[8];
            #pragma unroll
            for (int k = 0; k < 8; ++k) split_bf(vv[k], h[k], lo[k]);
            uint4 uh, ul;
            uh.x = packbf(h[0], h[1]); uh.y = packbf(h[2], h[3]); uh.z = packbf(h[4], h[5]); uh.w = packbf(h[6], h[7]);
            ul.x = packbf(lo[0], lo[1]); ul.y = packbf(lo[2], lo[3]); ul.z = packbf(lo[4], lo[5]); ul.w = packbf(lo[6], lo[7]);
            *(uint4*)&qCh[gaddr] = uh;
            *(uint4*)&qCl[gaddr] = ul;
            // trace (cov, diag blocks, straight pass only)
            if (MODE == 3 && bx == by && pass == 0) {
                int d = grow - gcol;
                if (d >= 0 && d < 8) atomicAdd(&trp[bz], vv[d]);
            }
            // colsum partials
            if (CSUM == 1) {
                #pragma unroll
                for (int k = 0; k < 8; ++k) cp[k] += vv[k];
            } else if (CSUM == 2) {
                float wgt = vin[bz * 512 + grow];
                #pragma unroll
                for (int k = 0; k < 8; ++k) cp[k] += wgt * vv[k];
            }
        }
        if (CSUM) {     // block-reduce 16 row-groups -> 128 cols, 1 atomic/col
            __syncthreads();
            #pragma unroll
            for (int k = 0; k < 8; ++k) colred[lr * 128 + lc0 + k] = cp[k];
            __syncthreads();
            if (tid < 128) {
                float s = 0.f;
                #pragma unroll
                for (int r = 0; r < 16; ++r) s += colred[r * 128 + tid];
                atomicAdd(&csum[bz * 512 + gc0 + tid], s);
            }
        }
    }
}

// ---------- v1 = 1.5*c0/tr - 0.5*c1 ----------
__global__ __launch_bounds__(512) void vkernA(const float* __restrict__ c0,
        const float* __restrict__ c1, const float* __restrict__ tr, float* __restrict__ v) {
    int b = blockIdx.x, c = threadIdx.x;
    float invt = 1.0f / tr[b];
    v[b * 512 + c] = 1.5f * c0[b * 512 + c] * invt - 0.5f * c1[b * 512 + c];
}

// ---------- v = 1.5*v - 0.5*vacc ----------
__global__ __launch_bounds__(512) void vkernB(const float* __restrict__ vacc, float* __restrict__ v) {
    int i = blockIdx.x * 512 + threadIdx.x;
    v[i] = 1.5f * v[i] - 0.5f * vacc[i];
}

// ---------- out = x * v[ch]/512*sqrt(tr[b]) ----------
__global__ __launch_bounds__(256) void scale_x(const float* __restrict__ x,
        const float* __restrict__ v, const float* __restrict__ tr,
        float* __restrict__ out) {
    size_t i = (size_t)blockIdx.x * 256 + threadIdx.x;
    size_t ch = i / 196;
    int b = (int)(ch >> 9);
    float sc = v[ch] * (1.0f / 512.0f) * sqrtf(tr[b]);
    float4 vv = ((const float4*)x)[i];
    vv.x *= sc; vv.y *= sc; vv.z *= sc; vv.w *= sc;
    ((float4*)out)[i] = vv;
}

extern "C" void kernel_launch(void* const* d_in, const int* in_sizes, int n_in,
                              void* d_out, int out_size, void* d_ws, size_t ws_size,
                              hipStream_t stream) {
    const float* x = (const float*)d_in[0];
    float* out = (float*)d_out;
    char* ws = (char*)d_ws;

    const size_t PLANE  = (size_t)32 * 512 * 512 * 2;   // 16.78 MB bf16 plane
    const size_t XPLANE = (size_t)32 * 512 * 800 * 2;   // 26.21 MB padded Xc plane

    float* tr   = (float*)(ws);                          // 32 f (atomic)
    float* c0   = (float*)(ws + 4096);                   // 32*512 colsum(cov)
    float* c1   = (float*)(ws + 4096 + 65536);           // 32*512 colsum(S0)
    float* vacc = (float*)(ws + 4096 + 2 * 65536);       // 4 x 32*512
    float* v    = (float*)(ws + 4096 + 6 * 65536);       // 32*512
    char* big = ws + (1 << 20);
    unsigned short* Ah = (unsigned short*)(big);                 // cov/M ping
    unsigned short* Al = (unsigned short*)(big + PLANE);
    char* R0 = big + 2 * PLANE;
    unsigned short* Xh = (unsigned short*)(R0);                  // dead after cov
    unsigned short* Xl = (unsigned short*)(R0 + XPLANE);
    unsigned short* Sh = (unsigned short*)(R0);                  // S = M^2 (overlaps X)
    unsigned short* Sl = (unsigned short*)(R0 + PLANE);
    size_t need = (1 << 20) + 2 * PLANE + 2 * XPLANE + 2 * PLANE;
    unsigned short *Bh, *Bl;                                      // M pong
    if (ws_size >= need) {
        Bh = (unsigned short*)(R0 + 2 * XPLANE);
        Bl = (unsigned short*)(R0 + 2 * XPLANE + PLANE);
    } else {                                              // d_out scratch (51.4 MB >= 33.5 MB)
        Bh = (unsigned short*)out;
        Bl = (unsigned short*)out + (size_t)32 * 512 * 512;
    }

    hipMemsetAsync(ws, 0, 4096 + 7 * 65536, stream);     // zero all accumulators

    // 1) center + split
    center_convert<<<32 * 512, 256, 0, stream>>>(x, Xh, Xl);
    // 2) cov = Xc@Xc^T/784 (tri, batch-major grid); fused trace + colsum(cov)->c0
    gemm_tri<3, 1, 0><<<320, 256, 0, stream>>>(Xh, Xl, Xh, Xl, nullptr, nullptr, nullptr, nullptr,
                                               Ah, Al, tr, c0, nullptr, 800, 800, 1.0f / 784.0f);
    // 3) S0 = cov^2/tr^2 ; fused colsum(S0)->c1
    gemm_tri<0, 1, 1><<<320, 256, 0, stream>>>(Ah, Al, Ah, Al, nullptr, nullptr, nullptr, nullptr,
                                               Sh, Sl, tr, c1, nullptr, 512, 512, 1.0f);
    // 4) v1 = 1.5*c0/tr - 0.5*c1
    vkernA<<<32, 512, 0, stream>>>(c0, c1, tr, v);
    // 5) M1 = 0.25(9*cov/tr - 6*S0 + cov@S0/tr) ; fused vacc0 = v1 @ M1
    gemm_tri<1, 2, 1><<<320, 256, 0, stream>>>(Ah, Al, Sh, Sl, Ah, Al, Sh, Sl,
                                               Bh, Bl, tr, vacc + 0 * 16384, v, 512, 512, 1.0f);
    vkernB<<<32, 512, 0, stream>>>(vacc + 0 * 16384, v);
    // 6) iters 1..3: S = M^2 ; M' = 0.25(9M - 6S + M@S) + fused v-partial ; v update
    unsigned short *Mh_ = Bh, *Ml_ = Bl, *Nh = Ah, *Nl = Al;
    for (int j = 1; j < 4; ++j) {
        gemm_tri<0, 0, 0><<<320, 256, 0, stream>>>(Mh_, Ml_, Mh_, Ml_, nullptr, nullptr, nullptr, nullptr,
                                                   Sh, Sl, tr, nullptr, nullptr, 512, 512, 1.0f);
        gemm_tri<1, 2, 0><<<320, 256, 0, stream>>>(Mh_, Ml_, Sh, Sl, Mh_, Ml_, Sh, Sl,
                                                   Nh, Nl, tr, vacc + (size_t)j * 16384, v, 512, 512, 1.0f);
        vkernB<<<32, 512, 0, stream>>>(vacc + (size_t)j * 16384, v);
        unsigned short* t1 = Mh_; Mh_ = Nh; Nh = t1;
        unsigned short* t2 = Ml_; Ml_ = Nl; Nl = t2;
    }
    // 7) out = x * v/512 * sqrt(tr)
    scale_x<<<12544, 256, 0, stream>>>(x, v, tr, out);
}

// Round 5
// 486.162 us; speedup vs baseline: 3.1254x; 1.0404x over previous
//
#include <hip/hip_runtime.h>
#include <math.h>

typedef short bf8 __attribute__((ext_vector_type(8)));   // 8 bf16 = 4 VGPRs
typedef float f4 __attribute__((ext_vector_type(4)));

__device__ inline unsigned short f2bf(float f) {          // RNE f32 -> bf16
    unsigned int u = __float_as_uint(f);
    u = u + 0x7fffu + ((u >> 16) & 1u);
    return (unsigned short)(u >> 16);
}
__device__ inline float bf2f(unsigned short h) {
    return __uint_as_float(((unsigned int)h) << 16);
}
__device__ inline void split_bf(float v, unsigned short& h, unsigned short& l) {
    h = f2bf(v);
    l = f2bf(v - bf2f(h));
}
__device__ inline unsigned int packbf(unsigned short a, unsigned short b) {
    return (unsigned int)a | ((unsigned int)b << 16);
}
__device__ inline void async16(const void* g, void* l) {
    __builtin_amdgcn_global_load_lds(
        (const __attribute__((address_space(1))) unsigned int*)g,
        (__attribute__((address_space(3))) unsigned int*)l, 16, 0, 0);
}

// ---------- fuse row-mean + center + bf16 hi/lo split (K padded 784->800 with zeros) ----------
__global__ __launch_bounds__(256) void center_convert(const float* __restrict__ x,
        unsigned short* __restrict__ Xh, unsigned short* __restrict__ Xl) {
    int row = blockIdx.x;                       // b*512 + c
    const float* xr = x + (size_t)row * 784;
    int t = threadIdx.x;
    float4 vv = {0.f, 0.f, 0.f, 0.f};
    if (t < 196) vv = *(const float4*)(xr + t * 4);
    float s = vv.x + vv.y + vv.z + vv.w;
    #pragma unroll
    for (int o = 32; o > 0; o >>= 1) s += __shfl_down(s, o, 64);
    __shared__ float red[4];
    int lane = t & 63, wv = t >> 6;
    if (lane == 0) red[wv] = s;
    __syncthreads();
    float m = (red[0] + red[1] + red[2] + red[3]) * (1.0f / 784.0f);
    if (t < 200) {
        ushort4 hh = {0, 0, 0, 0}, ll = {0, 0, 0, 0};
        if (t < 196) {
            split_bf(vv.x - m, hh.x, ll.x);
            split_bf(vv.y - m, hh.y, ll.y);
            split_bf(vv.z - m, hh.z, ll.z);
            split_bf(vv.w - m, hh.w, ll.w);
        }
        *(ushort4*)&Xh[(size_t)row * 800 + t * 4] = hh;
        *(ushort4*)&Xl[(size_t)row * 800 + t * 4] = ll;
    }
}

// ---------- full-grid bf16x3 NT GEMM, 128x128 tile, BK=32, 512 thr (8 waves), dbuf LDS ----------
// grid: bid = tile*32 + bz (bz fastest => batch bz on XCD bz%8); tile: by = t>>2, bx = t&3.
// 2 blocks/CU exactly, 4 waves/SIMD.
// MODE 0: C = A@B (S = M^2); ITER0: C *= invtr^2; CSUM=1 -> colsum
// MODE 1: C = 0.25(9*M*sc - 6*S + (A@B)*sc), sc = ITER0? invtr : 1; CSUM=2 -> vacc += vin.C
// MODE 3: C = (A@B)*cscale (cov); fused trace; CSUM=1 -> colsum(cov)
template<int MODE, int CSUM, int ITER0>
__global__ __launch_bounds__(512, 4) void gemm_full(
        const unsigned short* __restrict__ Ah, const unsigned short* __restrict__ Al,
        const unsigned short* __restrict__ Bh, const unsigned short* __restrict__ Bl,
        const unsigned short* __restrict__ Mh, const unsigned short* __restrict__ Ml,
        const unsigned short* __restrict__ Sh, const unsigned short* __restrict__ Sl,
        unsigned short* __restrict__ Ch, unsigned short* __restrict__ Cl,
        float* __restrict__ trp, float* __restrict__ csum, const float* __restrict__ vin,
        int K, int lda, float cscale) {
    __shared__ __align__(16) char smem[74240];   // 2x32768 staging | 128*129 f32 tile + colred
    unsigned short* stage = (unsigned short*)smem;
    float* tilef  = (float*)smem;
    float* colred = (float*)(smem + 66048);      // [16][128]

    int bid = blockIdx.x;
    int bz = bid & 31;
    int tt = bid >> 5;
    int by = tt >> 2, bx = tt & 3;

    size_t sAB = (size_t)512 * lda;
    size_t sC  = (size_t)512 * 512;
    const unsigned short* pAh = Ah + (size_t)bz * sAB;
    const unsigned short* pAl = Al + (size_t)bz * sAB;
    const unsigned short* pBh = Bh + (size_t)bz * sAB;
    const unsigned short* pBl = Bl + (size_t)bz * sAB;

    int tid = threadIdx.x;
    int w = tid >> 6, l = tid & 63;
    int rb0 = by * 128, cb0 = bx * 128;

    // staging: wave w handles plane sp = w>>1 (0:Ah 1:Al 2:Bh 3:Bl), half = w&1.
    // plane slot s (0..511): row = s>>2, k-slot g = (s&3)^((row>>1)&3) (swizzled)
    int sp = w >> 1, shalf = w & 1;
    const unsigned short* gp = (sp == 0) ? pAh : (sp == 1) ? pAl : (sp == 2) ? pBh : pBl;
    int rowbase = (sp < 2) ? rb0 : cb0;
    size_t goff[4];
    int ldsoff[4];
    #pragma unroll
    for (int q = 0; q < 4; ++q) {
        int s0 = shalf * 256 + q * 64;       // wave-uniform slot base
        int s = s0 + l;
        int r = s >> 2, g = (s & 3) ^ ((r >> 1) & 3);
        goff[q] = (size_t)(rowbase + r) * lda + g * 8;
        ldsoff[q] = sp * 4096 + s0 * 8;      // shorts, wave-uniform
    }

    f4 zero4 = {0.f, 0.f, 0.f, 0.f};
    f4 acc[2][4];
    #pragma unroll
    for (int i = 0; i < 2; ++i)
        #pragma unroll
        for (int j = 0; j < 4; ++j) acc[i][j] = zero4;

    int fr = l & 15, quad = l >> 4;
    int sw = quad ^ ((fr >> 1) & 3);
    int wr = w >> 1, wc = w & 1;             // wave tile: rows [wr*32,+32), cols [wc*64,+64)
    int NK = K >> 5;

    {   // prologue: stage chunk 0 into buf 0
        #pragma unroll
        for (int q = 0; q < 4; ++q) async16(gp + goff[q], stage + ldsoff[q]);
    }
    for (int ki = 0; ki < NK; ++ki) {
        __syncthreads();                     // drains buf[ki&1] (vmcnt0 + barrier)
        if (ki + 1 < NK) {
            int k0 = (ki + 1) << 5;
            unsigned short* sb2 = stage + ((ki + 1) & 1) * 16384;
            #pragma unroll
            for (int q = 0; q < 4; ++q) async16(gp + goff[q] + k0, sb2 + ldsoff[q]);
        }
        const unsigned short* sb = stage + (ki & 1) * 16384;
        bf8 ah[2], alo[2], bh[4], blo[4];
        #pragma unroll
        for (int i = 0; i < 2; ++i) {
            int oa = ((wr * 32 + i * 16 + fr) * 4 + sw) * 8;
            ah[i]  = *(const bf8*)&sb[0 * 4096 + oa];
            alo[i] = *(const bf8*)&sb[1 * 4096 + oa];
        }
        #pragma unroll
        for (int j = 0; j < 4; ++j) {
            int ob = ((wc * 64 + j * 16 + fr) * 4 + sw) * 8;
            bh[j]  = *(const bf8*)&sb[2 * 4096 + ob];
            blo[j] = *(const bf8*)&sb[3 * 4096 + ob];
        }
        #pragma unroll
        for (int i = 0; i < 2; ++i)
            #pragma unroll
            for (int j = 0; j < 4; ++j) {
                acc[i][j] = __builtin_amdgcn_mfma_f32_16x16x32_bf16(ah[i],  bh[j],  acc[i][j], 0, 0, 0);
                acc[i][j] = __builtin_amdgcn_mfma_f32_16x16x32_bf16(ah[i],  blo[j], acc[i][j], 0, 0, 0);
                acc[i][j] = __builtin_amdgcn_mfma_f32_16x16x32_bf16(alo[i], bh[j],  acc[i][j], 0, 0, 0);
            }
    }

    // ---- epilogue: acc -> f32 LDS tile [128][129] ----
    __syncthreads();
    #pragma unroll
    for (int i = 0; i < 2; ++i) {
        int rloc = wr * 32 + i * 16 + quad * 4;
        #pragma unroll
        for (int j = 0; j < 4; ++j) {
            int cloc = wc * 64 + j * 16 + fr;
            #pragma unroll
            for (int r = 0; r < 4; ++r) tilef[(rloc + r) * 129 + cloc] = acc[i][j][r];
        }
    }
    __syncthreads();

    float invtr_e = 1.0f;
    if ((MODE == 0 || MODE == 1) && ITER0) invtr_e = 1.0f / trp[bz];
    const float sc_g = (MODE == 3) ? cscale
                      : (MODE == 0 ? (ITER0 ? invtr_e * invtr_e : 1.0f)
                                   : (ITER0 ? invtr_e : 1.0f));

    unsigned short* qCh = Ch + (size_t)bz * sC;
    unsigned short* qCl = Cl + (size_t)bz * sC;
    const unsigned short* qMh = (MODE == 1) ? Mh + (size_t)bz * sC : nullptr;
    const unsigned short* qMl = (MODE == 1) ? Ml + (size_t)bz * sC : nullptr;
    const unsigned short* qSh = (MODE == 1) ? Sh + (size_t)bz * sC : nullptr;
    const unsigned short* qSl = (MODE == 1) ? Sl + (size_t)bz * sC : nullptr;

    int lr = tid >> 4, lc0 = (tid & 15) * 8;     // lr 0..31
    float cp[8] = {0.f, 0.f, 0.f, 0.f, 0.f, 0.f, 0.f, 0.f};
    #pragma unroll
    for (int p = 0; p < 4; ++p) {
        int row = lr + p * 32;
        int grow = rb0 + row, gcol = cb0 + lc0;
        float vv[8];
        #pragma unroll
        for (int k = 0; k < 8; ++k) vv[k] = tilef[row * 129 + lc0 + k];
        size_t gaddr = (size_t)grow * 512 + gcol;
        if (MODE == 3 || MODE == 0) {
            #pragma unroll
            for (int k = 0; k < 8; ++k) vv[k] *= sc_g;
        }
        if (MODE == 1) {
            uint4 mh = *(const uint4*)&qMh[gaddr], ml = *(const uint4*)&qMl[gaddr];
            uint4 sh = *(const uint4*)&qSh[gaddr], sl = *(const uint4*)&qSl[gaddr];
            const unsigned int* mhp = (const unsigned int*)&mh; const unsigned int* mlp = (const unsigned int*)&ml;
            const unsigned int* shp = (const unsigned int*)&sh; const unsigned int* slp = (const unsigned int*)&sl;
            #pragma unroll
            for (int k = 0; k < 8; ++k) {
                unsigned int hm = mhp[k >> 1], lm = mlp[k >> 1], hs = shp[k >> 1], ls = slp[k >> 1];
                float mval = bf2f((unsigned short)((k & 1) ? (hm >> 16) : (hm & 0xffffu)))
                           + bf2f((unsigned short)((k & 1) ? (lm >> 16) : (lm & 0xffffu)));
                float sval = bf2f((unsigned short)((k & 1) ? (hs >> 16) : (hs & 0xffffu)))
                           + bf2f((unsigned short)((k & 1) ? (ls >> 16) : (ls & 0xffffu)));
                vv[k] = 0.25f * (9.0f * mval * sc_g - 6.0f * sval + vv[k] * sc_g);
            }
        }
        unsigned short h[8], lo[8];
        #pragma unroll
        for (int k = 0; k < 8; ++k) split_bf(vv[k], h[k], lo[k]);
        uint4 uh, ul;
        uh.x = packbf(h[0], h[1]); uh.y = packbf(h[2], h[3]); uh.z = packbf(h[4], h[5]); uh.w = packbf(h[6], h[7]);
        ul.x = packbf(lo[0], lo[1]); ul.y = packbf(lo[2], lo[3]); ul.z = packbf(lo[4], lo[5]); ul.w = packbf(lo[6], lo[7]);
        *(uint4*)&qCh[gaddr] = uh;
        *(uint4*)&qCl[gaddr] = ul;
        if (MODE == 3 && bx == by) {            // trace (diag tiles)
            int d = row - lc0;
            if (d >= 0 && d < 8) atomicAdd(&trp[bz], vv[d]);
        }
        if (CSUM == 1) {
            #pragma unroll
            for (int k = 0; k < 8; ++k) cp[k] += vv[k];
        } else if (CSUM == 2) {
            float wgt = vin[bz * 512 + grow];
            #pragma unroll
            for (int k = 0; k < 8; ++k) cp[k] += wgt * vv[k];
        }
    }
    if (CSUM) {     // block-reduce 32 row-groups -> 128 cols (two rounds), 1 atomic/col
        __syncthreads();
        if (lr >= 16) {
            #pragma unroll
            for (int k = 0; k < 8; ++k) colred[(lr - 16) * 128 + lc0 + k] = cp[k];
        }
        __syncthreads();
        if (lr < 16) {
            #pragma unroll
            for (int k = 0; k < 8; ++k) colred[lr * 128 + lc0 + k] += cp[k];
        }
        __syncthreads();
        if (tid < 128) {
            float s = 0.f;
            #pragma unroll
            for (int r = 0; r < 16; ++r) s += colred[r * 128 + tid];
            atomicAdd(&csum[bz * 512 + cb0 + tid], s);
        }
    }
}

// ---------- v1 = 1.5*c0/tr - 0.5*c1 ----------
__global__ __launch_bounds__(512) void vkernA(const float* __restrict__ c0,
        const float* __restrict__ c1, const float* __restrict__ tr, float* __restrict__ v) {
    int b = blockIdx.x, c = threadIdx.x;
    float invt = 1.0f / tr[b];
    v[b * 512 + c] = 1.5f * c0[b * 512 + c] * invt - 0.5f * c1[b * 512 + c];
}

// ---------- v = 1.5*v - 0.5*vacc ----------
__global__ __launch_bounds__(512) void vkernB(const float* __restrict__ vacc, float* __restrict__ v) {
    int i = blockIdx.x * 512 + threadIdx.x;
    v[i] = 1.5f * v[i] - 0.5f * vacc[i];
}

// ---------- out = x * v[ch]/512*sqrt(tr[b]) ----------
__global__ __launch_bounds__(256) void scale_x(const float* __restrict__ x,
        const float* __restrict__ v, const float* __restrict__ tr,
        float* __restrict__ out) {
    size_t i = (size_t)blockIdx.x * 256 + threadIdx.x;
    size_t ch = i / 196;
    int b = (int)(ch >> 9);
    float sc = v[ch] * (1.0f / 512.0f) * sqrtf(tr[b]);
    float4 vv = ((const float4*)x)[i];
    vv.x *= sc; vv.y *= sc; vv.z *= sc; vv.w *= sc;
    ((float4*)out)[i] = vv;
}

extern "C" void kernel_launch(void* const* d_in, const int* in_sizes, int n_in,
                              void* d_out, int out_size, void* d_ws, size_t ws_size,
                              hipStream_t stream) {
    const float* x = (const float*)d_in[0];
    float* out = (float*)d_out;
    char* ws = (char*)d_ws;

    const size_t PLANE  = (size_t)32 * 512 * 512 * 2;   // 16.78 MB bf16 plane
    const size_t XPLANE = (size_t)32 * 512 * 800 * 2;   // 26.21 MB padded Xc plane

    float* tr   = (float*)(ws);                          // 32 f (atomic)
    float* c0   = (float*)(ws + 4096);                   // 32*512 colsum(cov)
    float* c1   = (float*)(ws + 4096 + 65536);           // 32*512 colsum(S0)
    float* vacc = (float*)(ws + 4096 + 2 * 65536);       // 4 x 32*512
    float* v    = (float*)(ws + 4096 + 6 * 65536);       // 32*512
    char* big = ws + (1 << 20);
    unsigned short* Ah = (unsigned short*)(big);                 // cov/M ping
    unsigned short* Al = (unsigned short*)(big + PLANE);
    char* R0 = big + 2 * PLANE;
    unsigned short* Xh = (unsigned short*)(R0);                  // dead after cov
    unsigned short* Xl = (unsigned short*)(R0 + XPLANE);
    unsigned short* Sh = (unsigned short*)(R0);                  // S = M^2 (overlaps X)
    unsigned short* Sl = (unsigned short*)(R0 + PLANE);
    size_t need = (1 << 20) + 2 * PLANE + 2 * XPLANE + 2 * PLANE;
    unsigned short *Bh, *Bl;                                      // M pong
    if (ws_size >= need) {
        Bh = (unsigned short*)(R0 + 2 * XPLANE);
        Bl = (unsigned short*)(R0 + 2 * XPLANE + PLANE);
    } else {                                              // d_out scratch (51.4 MB >= 33.5 MB)
        Bh = (unsigned short*)out;
        Bl = (unsigned short*)out + (size_t)32 * 512 * 512;
    }

    hipMemsetAsync(ws, 0, 4096 + 7 * 65536, stream);     // zero all accumulators

    // 1) center + split
    center_convert<<<32 * 512, 256, 0, stream>>>(x, Xh, Xl);
    // 2) cov = Xc@Xc^T/784 (full grid, batch-major); fused trace + colsum(cov)->c0
    gemm_full<3, 1, 0><<<512, 512, 0, stream>>>(Xh, Xl, Xh, Xl, nullptr, nullptr, nullptr, nullptr,
                                                Ah, Al, tr, c0, nullptr, 800, 800, 1.0f / 784.0f);
    // 3) S0 = cov^2/tr^2 ; fused colsum(S0)->c1
    gemm_full<0, 1, 1><<<512, 512, 0, stream>>>(Ah, Al, Ah, Al, nullptr, nullptr, nullptr, nullptr,
                                                Sh, Sl, tr, c1, nullptr, 512, 512, 1.0f);
    // 4) v1 = 1.5*c0/tr - 0.5*c1
    vkernA<<<32, 512, 0, stream>>>(c0, c1, tr, v);
    // 5) M1 = 0.25(9*cov/tr - 6*S0 + cov@S0/tr) ; fused vacc0 = v1 @ M1
    gemm_full<1, 2, 1><<<512, 512, 0, stream>>>(Ah, Al, Sh, Sl, Ah, Al, Sh, Sl,
                                                Bh, Bl, tr, vacc + 0 * 16384, v, 512, 512, 1.0f);
    vkernB<<<32, 512, 0, stream>>>(vacc + 0 * 16384, v);
    // 6) iters 1..3: S = M^2 ; M' = 0.25(9M - 6S + M@S) + fused v-partial ; v update
    unsigned short *Mh_ = Bh, *Ml_ = Bl, *Nh = Ah, *Nl = Al;
    for (int j = 1; j < 4; ++j) {
        gemm_full<0, 0, 0><<<512, 512, 0, stream>>>(Mh_, Ml_, Mh_, Ml_, nullptr, nullptr, nullptr, nullptr,
                                                    Sh, Sl, tr, nullptr, nullptr, 512, 512, 1.0f);
        gemm_full<1, 2, 0><<<512, 512, 0, stream>>>(Mh_, Ml_, Sh, Sl, Mh_, Ml_, Sh, Sl,
                                                    Nh, Nl, tr, vacc + (size_t)j * 16384, v, 512, 512, 1.0f);
        vkernB<<<32, 512, 0, stream>>>(vacc + (size_t)j * 16384, v);
        unsigned short* t1 = Mh_; Mh_ = Nh; Nh = t1;
        unsigned short* t2 = Ml_; Ml_ = Nl; Nl = t2;
    }
    // 7) out = x * v/512 * sqrt(tr)
    scale_x<<<12544, 256, 0, stream>>>(x, v, tr, out);
}